// Round 13
// baseline (1140.400 us; speedup 1.0000x reference)
//
#include <hip/hip_runtime.h>
#include <hip/hip_bf16.h>

#define VOCAB 29
#define VEC   512
#define HID   1024
#define SEN   64
#define BATCH 2048

typedef __bf16 bf16_t;
typedef bf16_t bf16x8 __attribute__((ext_vector_type(8)));
typedef float  floatx4 __attribute__((ext_vector_type(4)));

// ---------------- prep: W_hh fp32 -> bf16 ----------------
__global__ void cvt_whh(const float* __restrict__ w, bf16_t* __restrict__ o, int n) {
    int i = blockIdx.x * blockDim.x + threadIdx.x;
    if (i < n) o[i] = (bf16_t)w[i];
}

// ---------------- prep: W_cls fp32 [65][1024] -> bf16 padded [80][1024] ----------------
__global__ void cvt_wcls(const float* __restrict__ w, bf16_t* __restrict__ o) {
    int i = blockIdx.x * blockDim.x + threadIdx.x;
    if (i >= 80 * HID) return;
    o[i] = (i < 65 * HID) ? (bf16_t)w[i] : (bf16_t)0.0f;
}

// ---------------- prep: proj[v][h] = dot(emb[v], W_ih[h]) (fp32) ----------------
__global__ void proj_kernel(const float* __restrict__ emb, const float* __restrict__ wih,
                            float* __restrict__ proj) {
    int idx = blockIdx.x * blockDim.x + threadIdx.x;
    if (idx >= VOCAB * HID) return;
    int v = idx / HID, h = idx % HID;
    const float* e = emb + v * VEC;
    const float* w = wih + h * VEC;
    float s = 0.f;
    for (int k = 0; k < VEC; k += 4) {
        float4 ev = *(const float4*)(e + k);
        float4 wv = *(const float4*)(w + k);
        s += ev.x * wv.x + ev.y * wv.y + ev.z * wv.z + ev.w * wv.w;
    }
    proj[idx] = s;
}

// exact identity tanh(x) = 1 - 2/(exp(2x)+1); fp32 rounding error << bf16 ulp
__device__ __forceinline__ float fast_tanh(float x) {
    float e = __expf(2.0f * x);
    return 1.0f - 2.0f / (e + 1.0f);
}

// async global->LDS 16B copy. LDS dest: wave-uniform base + lane*16 (HW rule).
__device__ __forceinline__ void load16_to_lds(const bf16_t* g, bf16_t* l) {
    auto gp = reinterpret_cast<const __attribute__((address_space(1))) unsigned int*>(
        reinterpret_cast<uintptr_t>(g));
    auto lp = reinterpret_cast<__attribute__((address_space(3))) unsigned int*>(
        static_cast<unsigned int>(reinterpret_cast<uintptr_t>(l)));
    __builtin_amdgcn_global_load_lds(gp, lp, 16, 0, 0);
}

// ============================================================================
// v14: 32x32 WAVE TILES (4m x 2n) + BATCHED A-GROUPS — the untried cell.
//   Session factor matrix: {16x64, 32x32} x {per-chunk refill, batched}.
//   v8/v13 (16x64): DS-bound — 1024 ds_read_b128 + 8-way-class conflicts
//   (6.6e7) = ~6.8us of the 10.35us step; batching was moot (v13 == v8).
//   v11/v12 (32x32, per-chunk): ring sunk -> exposed L2 latency, regressed.
//   v14: 32x32 halves DS traffic (512 reads, conflicts 3.3e7 measured in
//   v11) and moves the other half to the VMEM pipe (A x2 dup; 2 waves share
//   each m-slice -> L1 absorbs the dup) — different pipes, overlappable,
//   MFMA 2.07us underneath. Ring liveness via v13's proven batch-4 dbuf
//   (ag[2][4][2]=64 VGPR; total ~125 <= the measured 128-VGPR cap for
//   512-thr kernels). Everything else identical to v13 (staging, panel
//   sync fast/safe, early buffer_inv, ascending K -> numerics unchanged).
// ============================================================================
#define BM 128
#define BN 64
#define PANEL_BLKS 16
#define SB() __builtin_amdgcn_sched_barrier(0)

// issue A-loads for chunks C0..C0+3 into group buffer B (2 m-frags per chunk)
#define ISSUE_G4(B, C0)                                              \
    _Pragma("unroll")                                                \
    for (int j = 0; j < 4; j++) {                                    \
        ag[B][j][0] = *(const bf16x8*)(hA + ((C0) + j) * 32);        \
        ag[B][j][1] = *(const bf16x8*)(hA + 16 * HID + ((C0) + j) * 32); \
    }

// compute chunks C0..C0+3 from group buffer B: 4 x {2 ds_read_b128, 4 MFMA}
#define COMP_G4(B, C0)                                               \
    _Pragma("unroll")                                                \
    for (int j = 0; j < 4; j++) {                                    \
        const int c_ = (C0) + j;                                     \
        const int pq = ((4 * c_ + q) ^ l7) * 8;                      \
        bf16x8 b0 = *(const bf16x8*)&Bsh[nb + l16][pq];              \
        bf16x8 b1 = *(const bf16x8*)&Bsh[nb + 16 + l16][pq];         \
        bf16x8 a0 = ag[B][j][0], a1 = ag[B][j][1];                   \
        acc[0][0] = __builtin_amdgcn_mfma_f32_16x16x32_bf16(a0, b0, acc[0][0], 0, 0, 0); \
        acc[0][1] = __builtin_amdgcn_mfma_f32_16x16x32_bf16(a0, b1, acc[0][1], 0, 0, 0); \
        acc[1][0] = __builtin_amdgcn_mfma_f32_16x16x32_bf16(a1, b0, acc[1][0], 0, 0, 0); \
        acc[1][1] = __builtin_amdgcn_mfma_f32_16x16x32_bf16(a1, b1, acc[1][1], 0, 0, 0); \
    }

__global__ __launch_bounds__(512, 2)
void rnn_persist(const bf16_t* __restrict__ whh, const float* __restrict__ proj,
                 const int* __restrict__ x, bf16_t* hbuf, int* scnt)
{
    __shared__ __align__(16) bf16_t Bsh[BN][HID];   // exactly 128 KB -> 1 block/CU
    __shared__ int uni_sh;

    const int tid  = threadIdx.x;
    const int bx   = blockIdx.x, by = blockIdx.y;
    const int m0   = bx * BM;
    const int n0   = by * BN;
    const int wave = tid >> 6;         // 8 waves
    const int lane = tid & 63;
    const int q    = lane >> 4;
    const int l16  = lane & 15;
    const int l7   = l16 & 7;
    const int mpos = wave & 3;         // 4 m-positions x 32 rows
    const int nb   = (wave >> 2) * 32; // 2 n-positions x 32 cols (LDS row base)

    int* cnt   = scnt + bx * 64;            // per-panel counter (256B stride)
    int* xmask = scnt + (16 + bx) * 64;     // per-panel XCD mask

    // ---- stage W_hh slice ONCE: 8 waves x 8 rows per half; dest lane-linear
    //      (DMA rule), source 16B-chunk XOR'd: phys = glob ^ (r&7).
#pragma unroll
    for (int half = 0; half < 2; half++)
#pragma unroll
        for (int it = 0; it < 8; it++) {
            const int r = it * 8 + wave;
            load16_to_lds(whh + (n0 + r) * HID + half * 512 + (lane ^ (r & 7)) * 8,
                          &Bsh[r][half * 512 + lane * 8]);
        }

    // rows this lane owns (C/D row = q*4+reg within each 16-row m-frag)
    int rowl[8];
#pragma unroll
    for (int mf = 0; mf < 2; mf++)
#pragma unroll
        for (int r = 0; r < 4; r++)
            rowl[mf * 4 + r] = m0 + mpos * 32 + mf * 16 + q * 4 + r;
    const int ncol0 = n0 + nb + l16;   // + ni*16, ni = 0,1

    // ---- t = 0: h = tanh(proj[x[:,0]]) (h_prev = 0); 8 rows x 2 cols/lane
#pragma unroll
    for (int i = 0; i < 8; i++) {
        const int tok = x[rowl[i] * SEN + 0];
#pragma unroll
        for (int ni = 0; ni < 2; ni++) {
            const float v = proj[tok * HID + ncol0 + ni * 16];
            hbuf[rowl[i] * HID + ncol0 + ni * 16] = (bf16_t)fast_tanh(v);
        }
    }

    // tokens for t=1 (prefetched)
    int tk[8];
#pragma unroll
    for (int i = 0; i < 8; i++) tk[i] = x[rowl[i] * SEN + 1];

    // ---- first sync: ALWAYS full release/acquire; publishes XCD mask
    __syncthreads();   // drains t0 stores AND the B-DMA (vmcnt covers global_load_lds)
    if (tid == 0) {
        const int my_xcd = (int)__builtin_amdgcn_s_getreg((3 << 11) | 20);  // HW_REG_XCC_ID
        __hip_atomic_fetch_or(xmask, 1 << my_xcd, __ATOMIC_RELAXED, __HIP_MEMORY_SCOPE_AGENT);
        __hip_atomic_fetch_add(cnt, 1, __ATOMIC_RELEASE, __HIP_MEMORY_SCOPE_AGENT);
        while (__hip_atomic_load(cnt, __ATOMIC_ACQUIRE, __HIP_MEMORY_SCOPE_AGENT) < PANEL_BLKS)
            __builtin_amdgcn_s_sleep(1);
        const int m = __hip_atomic_load(xmask, __ATOMIC_RELAXED, __HIP_MEMORY_SCOPE_AGENT);
        uni_sh = ((m & (m - 1)) == 0);   // one XCD bit -> same-L2 fast path legal
    }
    __syncthreads();
    asm volatile("buffer_inv" ::: "memory");
    const int fast = uni_sh;

#pragma unroll 1
    for (int t = 1; t < SEN; t++) {
        const bf16_t* h_in  = hbuf + (size_t)((t + 1) & 1) * (BATCH * HID);
        bf16_t*       h_out = hbuf + (size_t)(t & 1) * (BATCH * HID);

        floatx4 acc[2][2];
#pragma unroll
        for (int i = 0; i < 2; i++)
#pragma unroll
            for (int j = 0; j < 2; j++) acc[i][j] = (floatx4){0.f, 0.f, 0.f, 0.f};

        // A-fragment base: lane (q,l16), m-frag mf -> h_in[m0+mpos*32+mf*16+l16][c*32+q*8]
        const bf16_t* hA = h_in + (size_t)(m0 + mpos * 32 + l16) * HID + q * 8;
        bf16x8 ag[2][4][2];   // 2 groups x 4 chunks x 2 m-frags = 64 VGPR

        // ---- pinned pipeline: batched ISSUE / COMPUTE, dbuf ----------------
        ISSUE_G4(0, 0)
        ISSUE_G4(1, 4)
        // proj rows for THIS step (tk prefetched last step); used at epilogue
        float pv[8][2];
#pragma unroll
        for (int i = 0; i < 8; i++) {
            const float* pr = proj + tk[i] * HID + ncol0;
            pv[i][0] = pr[0];
            pv[i][1] = pr[16];
        }
        SB();
#pragma unroll
        for (int g = 0; g < 8; g++) {
            COMP_G4(g & 1, g * 4)
            SB();
            if (g < 6) {
                ISSUE_G4(g & 1, (g + 2) * 4)
                SB();
            }
            if (g == 5 && t < SEN - 1) {   // tokens for t+1, off critical path
#pragma unroll
                for (int i = 0; i < 8; i++) tk[i] = x[rowl[i] * SEN + t + 1];
            }
        }

        // epilogue: + proj, tanh, store (8 rows x 2 cols per lane)
#pragma unroll
        for (int mf = 0; mf < 2; mf++)
#pragma unroll
            for (int r = 0; r < 4; r++)
#pragma unroll
                for (int ni = 0; ni < 2; ni++) {
                    const int i = mf * 4 + r;
                    const float v = acc[mf][ni][r] + pv[i][ni];
                    h_out[rowl[i] * HID + ncol0 + ni * 16] = (bf16_t)fast_tanh(v);
                }

        // ---- panel sync (skip after final step) ---------------------------
        if (t < SEN - 1) {
            __syncthreads();   // vmcnt(0): this block's h stores are in L2
            // inv EARLY (overlaps the spin); safe: L2 is the intra-XCD
            // coherence point and no h-address is touched before the pass.
            asm volatile("buffer_inv" ::: "memory");
            if (fast) {        // same-L2: relaxed counter, no cache maintenance
                if (tid == 0) {
                    __hip_atomic_fetch_add(cnt, 1, __ATOMIC_RELAXED, __HIP_MEMORY_SCOPE_AGENT);
                    while (__hip_atomic_load(cnt, __ATOMIC_RELAXED, __HIP_MEMORY_SCOPE_AGENT)
                           < PANEL_BLKS * (t + 1))
                        __builtin_amdgcn_s_sleep(1);
                }
            } else {           // cross-XCD fallback: full release/acquire
                if (tid == 0) {
                    __hip_atomic_fetch_add(cnt, 1, __ATOMIC_RELEASE, __HIP_MEMORY_SCOPE_AGENT);
                    while (__hip_atomic_load(cnt, __ATOMIC_ACQUIRE, __HIP_MEMORY_SCOPE_AGENT)
                           < PANEL_BLKS * (t + 1))
                        __builtin_amdgcn_s_sleep(1);
                }
            }
            __syncthreads();
        }
    }
}

#undef ISSUE_G4
#undef COMP_G4

// ---------------- classifier: out = h @ W_cls^T + b_cls via MFMA (proven R2) ----------------
#define CBM 128
#define CLDK 72
__global__ __launch_bounds__(256)
void classifier_mfma(const bf16_t* __restrict__ h, const bf16_t* __restrict__ wcls,
                     const float* __restrict__ bcls, float* __restrict__ out)
{
    __shared__ __align__(16) bf16_t Ash[CBM][CLDK];
    __shared__ __align__(16) bf16_t Bsh[80][CLDK];

    const int tid = threadIdx.x;
    const int m0 = blockIdx.x * CBM;
    const int wave = tid >> 6, lane = tid & 63;
    const int wm = wave * 32;
    const int q = lane >> 4, l16 = lane & 15;

    floatx4 acc[2][5];
#pragma unroll
    for (int i = 0; i < 2; i++)
#pragma unroll
        for (int j = 0; j < 5; j++) acc[i][j] = (floatx4){0.f, 0.f, 0.f, 0.f};

    for (int kk = 0; kk < HID; kk += 64) {
#pragma unroll
        for (int it = 0; it < 4; it++) {
            int idx = tid + it * 256, r = idx >> 3, c = (idx & 7) * 8;
            *(uint4*)&Ash[r][c] = *(const uint4*)&h[(m0 + r) * HID + kk + c];
        }
#pragma unroll
        for (int it = 0; it < 3; it++) {
            int idx = tid + it * 256;
            if (idx < 640) {
                int r = idx >> 3, c = (idx & 7) * 8;
                *(uint4*)&Bsh[r][c] = *(const uint4*)&wcls[r * HID + kk + c];
            }
        }
        __syncthreads();
#pragma unroll
        for (int ks = 0; ks < 64; ks += 32) {
            bf16x8 af[2], bfr[5];
#pragma unroll
            for (int mi = 0; mi < 2; mi++)
                af[mi] = *(const bf16x8*)&Ash[wm + mi * 16 + l16][ks + q * 8];
#pragma unroll
            for (int ni = 0; ni < 5; ni++)
                bfr[ni] = *(const bf16x8*)&Bsh[ni * 16 + l16][ks + q * 8];
#pragma unroll
            for (int mi = 0; mi < 2; mi++)
#pragma unroll
                for (int ni = 0; ni < 5; ni++)
                    acc[mi][ni] = __builtin_amdgcn_mfma_f32_16x16x32_bf16(
                        af[mi], bfr[ni], acc[mi][ni], 0, 0, 0);
        }
        __syncthreads();
    }

#pragma unroll
    for (int mi = 0; mi < 2; mi++) {
#pragma unroll
        for (int r = 0; r < 4; r++) {
            int gm = m0 + wm + mi * 16 + q * 4 + r;
#pragma unroll
            for (int ni = 0; ni < 5; ni++) {
                int gn = ni * 16 + l16;
                if (gn < SEN + 1)
                    out[gm * (SEN + 1) + gn] = acc[mi][ni][r] + bcls[gn];
            }
        }
    }
}

extern "C" void kernel_launch(void* const* d_in, const int* in_sizes, int n_in,
                              void* d_out, int out_size, void* d_ws, size_t ws_size,
                              hipStream_t stream)
{
    const int*   x     = (const int*)  d_in[0];
    const float* emb   = (const float*)d_in[1];
    const float* w_ih  = (const float*)d_in[2];
    const float* w_hh  = (const float*)d_in[3];
    const float* w_cls = (const float*)d_in[4];
    const float* b_cls = (const float*)d_in[5];
    float* out = (float*)d_out;

    char* ws = (char*)d_ws;
    bf16_t* whh_bf  = (bf16_t*)ws;                                  // 2 MB
    float*  proj    = (float*)(ws + (2u << 20));                    // 128 KB
    bf16_t* wcls_bf = (bf16_t*)(ws + (2u << 20) + (128u << 10));    // 160 KB
    bf16_t* h0      = (bf16_t*)(ws + (2u << 20) + (288u << 10));    // 4 MB
    bf16_t* h1      = (bf16_t*)(ws + (6u << 20) + (288u << 10));    // 4 MB
    int*    scnt    = (int*)   (ws + (10u << 20) + (288u << 10));   // sync area

    hipMemsetAsync(scnt, 0, 16384, stream);
    cvt_whh<<<(HID * HID) / 256, 256, 0, stream>>>(w_hh, whh_bf, HID * HID);
    proj_kernel<<<(VOCAB * HID + 255) / 256, 256, 0, stream>>>(emb, w_ih, proj);
    cvt_wcls<<<(80 * HID) / 256, 256, 0, stream>>>(w_cls, wcls_bf);

    dim3 grid(BATCH / BM, HID / BN);   // (16,16) = 256 blocks = 1/CU (128 KB LDS)
    rnn_persist<<<grid, 512, 0, stream>>>(whh_bf, proj, x, h0, scnt);

    classifier_mfma<<<BATCH / CBM, 256, 0, stream>>>(h1, wcls_bf, b_cls, out);
}

// Round 14
// 827.037 us; speedup vs baseline: 1.3789x; 1.3789x over previous
//
#include <hip/hip_runtime.h>
#include <hip/hip_bf16.h>

#define VOCAB 29
#define VEC   512
#define HID   1024
#define SEN   64
#define BATCH 2048

typedef __bf16 bf16_t;
typedef bf16_t bf16x8 __attribute__((ext_vector_type(8)));
typedef float  floatx4 __attribute__((ext_vector_type(4)));

// exact identity tanh(x) = 1 - 2/(exp(2x)+1); fp32 rounding error << bf16 ulp
__device__ __forceinline__ float fast_tanh(float x) {
    float e = __expf(2.0f * x);
    return 1.0f - 2.0f / (e + 1.0f);
}

// ============================================================================
// v15: ONE FUSED PERSISTENT KERNEL. K-loop = v8 verbatim (652us, best of 14
// variants; v9-v14 all failed to beat it -> K-loop closed). This round
// removes the ~60us of non-loop time:
//   - W_hh cvt fused: block converts its fp32 slice straight into swizzled
//     Bsh via ds_write_b128 (manual writes need no DMA lane-linearity).
//   - proj fused: block computes its 29x64 slice into LDS (same float4 dot
//     loop -> bit-identical); epilogue pv reads become LDS-local.
//   - classifier fused as tail: one extra panel sync (target 16*64), then
//     by==0 blocks compute their panel's 128x65 logits, A from L2-hot h,
//     B converted from fp32 W_cls on the fly (same chunk order -> same sums).
//   Launches: 5 -> 2 (memset + kernel). LDS: 128K Bsh + 7.4K Psh = 136K,
//   still 1 block/CU. Numerics identical everywhere (absmax 0.0039).
// ============================================================================
#define BM 128
#define BN 64
#define PANEL_BLKS 16
#define SB() __builtin_amdgcn_sched_barrier(0)

__global__ __launch_bounds__(512, 2)
void rnn_all(const float* __restrict__ whh32, const float* __restrict__ emb,
             const float* __restrict__ wih, const float* __restrict__ wcls32,
             const float* __restrict__ bcls, const int* __restrict__ x,
             bf16_t* hbuf, float* out, int* scnt)
{
    __shared__ __align__(16) bf16_t Bsh[BN][HID];     // 128 KB, swizzled chunks
    __shared__ __align__(16) float  Psh[VOCAB][BN];   // 7.4 KB proj slice
    __shared__ int uni_sh;

    const int tid  = threadIdx.x;
    const int bx   = blockIdx.x, by = blockIdx.y;
    const int m0   = bx * BM;
    const int n0   = by * BN;
    const int wave = tid >> 6;         // 8 waves
    const int lane = tid & 63;
    const int wm   = wave * 16;        // wave tile 16 x 64 (m-split 8 ways)
    const int q    = lane >> 4;
    const int l16  = lane & 15;
    const int l7   = l16 & 7;

    int* cnt   = scnt + bx * 64;            // per-panel counter (256B stride)
    int* xmask = scnt + (16 + bx) * 64;     // per-panel XCD mask

    // ---- prologue 1: W_hh fp32 slice -> bf16, swizzled, straight into LDS.
    //      Slot (r,j) holds global chunk j^(r&7) (same layout the loop reads).
#pragma unroll
    for (int k = 0; k < 16; k++) {
        const int idx = tid + k * 512;          // 8192 16B-slots
        const int r = idx >> 7, j = idx & 127;
        const float* src = whh32 + (size_t)(n0 + r) * HID + (j ^ (r & 7)) * 8;
        float4 a = *(const float4*)src;
        float4 b = *(const float4*)(src + 4);
        bf16x8 v;
        v[0] = (bf16_t)a.x; v[1] = (bf16_t)a.y; v[2] = (bf16_t)a.z; v[3] = (bf16_t)a.w;
        v[4] = (bf16_t)b.x; v[5] = (bf16_t)b.y; v[6] = (bf16_t)b.z; v[7] = (bf16_t)b.w;
        *(bf16x8*)&Bsh[r][j * 8] = v;
    }

    // ---- prologue 2: proj slice Psh[v][col] = dot(emb[v], W_ih[n0+col])
    //      (exact same accumulation order as the old proj_kernel)
    for (int p = tid; p < VOCAB * BN; p += 512) {
        const int v = p / BN, col = p % BN;
        const float* e = emb + v * VEC;
        const float* w = wih + (n0 + col) * VEC;
        float s = 0.f;
        for (int kk = 0; kk < VEC; kk += 4) {
            float4 ev = *(const float4*)(e + kk);
            float4 wv = *(const float4*)(w + kk);
            s += ev.x * wv.x + ev.y * wv.y + ev.z * wv.z + ev.w * wv.w;
        }
        Psh[v][col] = s;
    }
    __syncthreads();   // Bsh + Psh ready

    // rows this lane owns (C/D row = q*4+reg, col = l16)
    int rowl[4];
#pragma unroll
    for (int r = 0; r < 4; r++) rowl[r] = m0 + wm + q * 4 + r;

    // ---- t = 0: h = tanh(proj[x[:,0]]) (h_prev = 0)
#pragma unroll
    for (int i = 0; i < 4; i++) {
        const int tok = x[rowl[i] * SEN + 0];
#pragma unroll
        for (int ni = 0; ni < 4; ni++) {
            const float v = Psh[tok][ni * 16 + l16];
            hbuf[rowl[i] * HID + n0 + ni * 16 + l16] = (bf16_t)fast_tanh(v);
        }
    }

    // tokens for t=1 (prefetched)
    int tk[4];
#pragma unroll
    for (int i = 0; i < 4; i++) tk[i] = x[rowl[i] * SEN + 1];

    // ---- first sync: ALWAYS full release/acquire; publishes XCD mask
    __syncthreads();   // drains t0 stores
    if (tid == 0) {
        const int my_xcd = (int)__builtin_amdgcn_s_getreg((3 << 11) | 20);  // HW_REG_XCC_ID
        __hip_atomic_fetch_or(xmask, 1 << my_xcd, __ATOMIC_RELAXED, __HIP_MEMORY_SCOPE_AGENT);
        __hip_atomic_fetch_add(cnt, 1, __ATOMIC_RELEASE, __HIP_MEMORY_SCOPE_AGENT);
        while (__hip_atomic_load(cnt, __ATOMIC_ACQUIRE, __HIP_MEMORY_SCOPE_AGENT) < PANEL_BLKS)
            __builtin_amdgcn_s_sleep(1);
        const int m = __hip_atomic_load(xmask, __ATOMIC_RELAXED, __HIP_MEMORY_SCOPE_AGENT);
        uni_sh = ((m & (m - 1)) == 0);   // one XCD bit -> same-L2 fast path legal
    }
    __syncthreads();
    asm volatile("buffer_inv" ::: "memory");
    const int fast = uni_sh;

    // ======================= v8 K-loop, verbatim ===========================
#pragma unroll 1
    for (int t = 1; t < SEN; t++) {
        const bf16_t* h_in  = hbuf + (size_t)((t + 1) & 1) * (BATCH * HID);
        bf16_t*       h_out = hbuf + (size_t)(t & 1) * (BATCH * HID);

        floatx4 acc[4];
#pragma unroll
        for (int j = 0; j < 4; j++) acc[j] = (floatx4){0.f, 0.f, 0.f, 0.f};

        const bf16_t* hA = h_in + (size_t)(m0 + wm + l16) * HID + q * 8;
        bf16x8 afr[4][1];   // 4-chunk ring

        // prologue: prefetch chunks 0..3
#pragma unroll
        for (int d = 0; d < 4; d++)
            afr[d][0] = *(const bf16x8*)(hA + d * 32);

        // proj rows for THIS step (tk prefetched last step) — from LDS now
        float pv[4][4];
#pragma unroll
        for (int i = 0; i < 4; i++)
#pragma unroll
            for (int ni = 0; ni < 4; ni++)
                pv[i][ni] = Psh[tk[i]][ni * 16 + l16];
        SB();

#pragma unroll
        for (int c = 0; c < 32; c++) {
            const int slot = c & 3;
            const int pq = ((4 * c + q) ^ l7) * 8;
            bf16x8 b0 = *(const bf16x8*)&Bsh[l16][pq];
            bf16x8 b1 = *(const bf16x8*)&Bsh[16 + l16][pq];
            bf16x8 b2 = *(const bf16x8*)&Bsh[32 + l16][pq];
            bf16x8 b3 = *(const bf16x8*)&Bsh[48 + l16][pq];
            bf16x8 a0 = afr[slot][0];
            acc[0] = __builtin_amdgcn_mfma_f32_16x16x32_bf16(a0, b0, acc[0], 0, 0, 0);
            acc[1] = __builtin_amdgcn_mfma_f32_16x16x32_bf16(a0, b1, acc[1], 0, 0, 0);
            acc[2] = __builtin_amdgcn_mfma_f32_16x16x32_bf16(a0, b2, acc[2], 0, 0, 0);
            acc[3] = __builtin_amdgcn_mfma_f32_16x16x32_bf16(a0, b3, acc[3], 0, 0, 0);
            if (c < 28) afr[slot][0] = *(const bf16x8*)(hA + (c + 4) * 32);
            if (c == 24 && t < SEN - 1) {
#pragma unroll
                for (int i = 0; i < 4; i++) tk[i] = x[rowl[i] * SEN + t + 1];
            }
            SB();
        }

        // epilogue: + proj, tanh, store
#pragma unroll
        for (int r = 0; r < 4; r++)
#pragma unroll
            for (int ni = 0; ni < 4; ni++) {
                float v = acc[ni][r] + pv[r][ni];
                h_out[rowl[r] * HID + n0 + ni * 16 + l16] = (bf16_t)fast_tanh(v);
            }

        // ---- panel sync (t=63 handled by the final sync below) ------------
        if (t < SEN - 1) {
            __syncthreads();   // vmcnt(0): this block's h stores are in L2
            asm volatile("buffer_inv" ::: "memory");   // early-inv (v13-proven)
            if (fast) {
                if (tid == 0) {
                    __hip_atomic_fetch_add(cnt, 1, __ATOMIC_RELAXED, __HIP_MEMORY_SCOPE_AGENT);
                    while (__hip_atomic_load(cnt, __ATOMIC_RELAXED, __HIP_MEMORY_SCOPE_AGENT)
                           < PANEL_BLKS * (t + 1))
                        __builtin_amdgcn_s_sleep(1);
                }
            } else {
                if (tid == 0) {
                    __hip_atomic_fetch_add(cnt, 1, __ATOMIC_RELEASE, __HIP_MEMORY_SCOPE_AGENT);
                    while (__hip_atomic_load(cnt, __ATOMIC_ACQUIRE, __HIP_MEMORY_SCOPE_AGENT)
                           < PANEL_BLKS * (t + 1))
                        __builtin_amdgcn_s_sleep(1);
                }
            }
            __syncthreads();
        }
    }

    // ================== fused classifier tail ==============================
    // final sync: make every panel's t=63 columns L2-visible
    __syncthreads();   // drain t=63 stores
    if (tid == 0) {
        if (fast)
            __hip_atomic_fetch_add(cnt, 1, __ATOMIC_RELAXED, __HIP_MEMORY_SCOPE_AGENT);
        else
            __hip_atomic_fetch_add(cnt, 1, __ATOMIC_RELEASE, __HIP_MEMORY_SCOPE_AGENT);
    }
    if (by != 0) return;   // 15/16 blocks done; one block per panel finishes

    if (tid == 0) {
        if (fast) {
            while (__hip_atomic_load(cnt, __ATOMIC_RELAXED, __HIP_MEMORY_SCOPE_AGENT)
                   < PANEL_BLKS * SEN)
                __builtin_amdgcn_s_sleep(1);
        } else {
            while (__hip_atomic_load(cnt, __ATOMIC_ACQUIRE, __HIP_MEMORY_SCOPE_AGENT)
                   < PANEL_BLKS * SEN)
                __builtin_amdgcn_s_sleep(1);
        }
    }
    __syncthreads();
    asm volatile("buffer_inv" ::: "memory");   // L1 refetch -> fresh L2 h

    // out[m0+wm .. +15][0..64] per wave; A from h (L2), B cvt'd from fp32 W_cls.
    // Same chunk order (c = 0..31) as the old classifier -> identical sums.
    {
        const bf16_t* h1 = hbuf + (size_t)((SEN - 1) & 1) * (BATCH * HID);
        const bf16_t* hA = h1 + (size_t)(m0 + wm + l16) * HID + q * 8;

        floatx4 acc[5];
#pragma unroll
        for (int j = 0; j < 5; j++) acc[j] = (floatx4){0.f, 0.f, 0.f, 0.f};

#pragma unroll 1
        for (int c = 0; c < 32; c++) {
            bf16x8 af = *(const bf16x8*)(hA + c * 32);
            bf16x8 bfr[5];
#pragma unroll
            for (int ni = 0; ni < 5; ni++) {
                const int gn = ni * 16 + l16;
                bf16x8 v;
                if (gn < SEN + 1) {
                    const float* src = wcls32 + (size_t)gn * HID + c * 32 + q * 8;
                    float4 a = *(const float4*)src;
                    float4 b = *(const float4*)(src + 4);
                    v[0] = (bf16_t)a.x; v[1] = (bf16_t)a.y; v[2] = (bf16_t)a.z; v[3] = (bf16_t)a.w;
                    v[4] = (bf16_t)b.x; v[5] = (bf16_t)b.y; v[6] = (bf16_t)b.z; v[7] = (bf16_t)b.w;
                } else {
                    v = (bf16x8){(bf16_t)0.f, (bf16_t)0.f, (bf16_t)0.f, (bf16_t)0.f,
                                 (bf16_t)0.f, (bf16_t)0.f, (bf16_t)0.f, (bf16_t)0.f};
                }
                bfr[ni] = v;
            }
#pragma unroll
            for (int ni = 0; ni < 5; ni++)
                acc[ni] = __builtin_amdgcn_mfma_f32_16x16x32_bf16(af, bfr[ni], acc[ni], 0, 0, 0);
        }

#pragma unroll
        for (int r = 0; r < 4; r++) {
            const int gm = m0 + wm + q * 4 + r;
#pragma unroll
            for (int ni = 0; ni < 5; ni++) {
                const int gn = ni * 16 + l16;
                if (gn < SEN + 1)
                    out[gm * (SEN + 1) + gn] = acc[ni][r] + bcls[gn];
            }
        }
    }
}

extern "C" void kernel_launch(void* const* d_in, const int* in_sizes, int n_in,
                              void* d_out, int out_size, void* d_ws, size_t ws_size,
                              hipStream_t stream)
{
    const int*   x     = (const int*)  d_in[0];
    const float* emb   = (const float*)d_in[1];
    const float* w_ih  = (const float*)d_in[2];
    const float* w_hh  = (const float*)d_in[3];
    const float* w_cls = (const float*)d_in[4];
    const float* b_cls = (const float*)d_in[5];
    float* out = (float*)d_out;

    char* ws = (char*)d_ws;
    bf16_t* h0   = (bf16_t*)ws;                   // 4 MB (t even)
    // h1 lives at ws + 4MB (t odd) — addressed via hbuf + BATCH*HID
    int*    scnt = (int*)(ws + (8u << 20));       // sync area

    hipMemsetAsync(scnt, 0, 16384, stream);

    dim3 grid(BATCH / BM, HID / BN);   // (16,16) = 256 blocks = 1/CU (136 KB LDS)
    rnn_all<<<grid, 512, 0, stream>>>(w_hh, emb, w_ih, w_cls, b_cls, x, h0, out, scnt);
}